// Round 8
// baseline (28.534 us; speedup 1.0000x reference)
//
#include <hip/hip_runtime.h>
#include <hip/hip_bf16.h>

// Problem constants: B=16, NTX=1, S=4, OFDM=14, FFT=1024, NRX=4, NRXA=1, T=16.
// precoding_ind = arange(4) -> identity selection (folded into indexing).
#define NB    16
#define NS    4
#define NT    16
#define NOFDM 14
#define NFFT  1024
#define SITE  (NOFDM * NFFT)          // 14336 sites per b
#define NSITES (NB * SITE)            // 229376 threads total

// RNE float -> bf16 bits (fallback path only)
__device__ __forceinline__ unsigned short bf16_bits(float f) {
    unsigned int u = __float_as_uint(f);
    return (unsigned short)((u + 0x7FFFu + ((u >> 16) & 1u)) >> 16);
}

template <int MODE>   // 0: f32 real-part only (out_size=3670016); 1: bf16 interleaved pairs
__global__ __launch_bounds__(256) void zf_precoder_kernel(
    const float* __restrict__ xr, const float* __restrict__ xi,
    const float* __restrict__ hr, const float* __restrict__ hi,
    void* __restrict__ out_raw)
{
    const int gid = blockIdx.x * 256 + threadIdx.x;   // site id, exact grid
    if (gid >= NSITES) return;
    const int b   = gid / SITE;
    const int rem = gid - b * SITE;                   // ofdm*NFFT + fft

    // ---- load x (4 complex): x (B,1,S,OFDM,FFT) ----
    float Xr[NS], Xi[NS];
    const int xbase = b * (NS * SITE) + rem;
    #pragma unroll
    for (int s = 0; s < NS; ++s) {
        Xr[s] = xr[xbase + s * SITE];
        Xi[s] = xi[xbase + s * SITE];
    }

    // ---- load H (4x16 complex): h (B,4,1,1,16,OFDM,FFT) ----
    float Hr[NS][NT], Hi[NS][NT];
    const int hbase = b * (NS * NT * SITE) + rem;
    #pragma unroll
    for (int s = 0; s < NS; ++s) {
        #pragma unroll
        for (int t = 0; t < NT; ++t) {
            const int idx = hbase + (s * NT + t) * SITE;
            Hr[s][t] = hr[idx];
            Hi[s][t] = hi[idx];
        }
    }

    // ---- A = H * H^H (lower triangle, Hermitian) ----
    float Ar[NS][NS], Ai[NS][NS];
    #pragma unroll
    for (int i = 0; i < NS; ++i) {
        #pragma unroll
        for (int j = 0; j <= i; ++j) {
            float sr = 0.f, si = 0.f;
            #pragma unroll
            for (int t = 0; t < NT; ++t) {
                sr += Hr[i][t] * Hr[j][t] + Hi[i][t] * Hi[j][t];
                si += Hi[i][t] * Hr[j][t] - Hr[i][t] * Hi[j][t];
            }
            Ar[i][j] = sr;
            Ai[i][j] = si;
        }
    }

    // ---- complex Cholesky A = L L^H (in-place, 1/diag in invd) ----
    float invd[NS];
    #pragma unroll
    for (int j = 0; j < NS; ++j) {
        float s = Ar[j][j];
        #pragma unroll
        for (int k = 0; k < j; ++k)
            s -= Ar[j][k] * Ar[j][k] + Ai[j][k] * Ai[j][k];
        const float inv = 1.0f / sqrtf(fmaxf(s, 1e-20f));
        invd[j] = inv;
        #pragma unroll
        for (int i = j + 1; i < NS; ++i) {
            float sr = Ar[i][j], si = Ai[i][j];
            #pragma unroll
            for (int k = 0; k < j; ++k) {
                sr -= Ar[i][k] * Ar[j][k] + Ai[i][k] * Ai[j][k];
                si -= Ai[i][k] * Ar[j][k] - Ar[i][k] * Ai[j][k];
            }
            Ar[i][j] = sr * inv;
            Ai[i][j] = si * inv;
        }
    }

    // ---- forward solve L w = x ----
    float Wr[NS], Wi[NS];
    #pragma unroll
    for (int i = 0; i < NS; ++i) {
        float sr = Xr[i], si = Xi[i];
        #pragma unroll
        for (int k = 0; k < i; ++k) {
            sr -= Ar[i][k] * Wr[k] - Ai[i][k] * Wi[k];
            si -= Ar[i][k] * Wi[k] + Ai[i][k] * Wr[k];
        }
        Wr[i] = sr * invd[i];
        Wi[i] = si * invd[i];
    }

    // ---- back solve L^H z = w ----
    float Zr[NS], Zi[NS];
    #pragma unroll
    for (int i = NS - 1; i >= 0; --i) {
        float sr = Wr[i], si = Wi[i];
        #pragma unroll
        for (int k = i + 1; k < NS; ++k) {
            sr -= Ar[k][i] * Zr[k] + Ai[k][i] * Zi[k];
            si -= Ar[k][i] * Zi[k] - Ai[k][i] * Zr[k];
        }
        Zr[i] = sr * invd[i];
        Zi[i] = si * invd[i];
    }

    // ---- y[t] = sum_s conj(H[s][t]) * z[s] ----
    // Output complex array is (B,1,T,OFDM,FFT); site idx = b*(NT*SITE) + t*SITE + rem.
    // MODE 0: harness stores ref.astype(float32) == REAL PART only -> float* of 3.67M.
    const int obase = b * (NT * SITE) + rem;
    #pragma unroll
    for (int t = 0; t < NT; ++t) {
        float yr = 0.f, yi = 0.f;
        #pragma unroll
        for (int s = 0; s < NS; ++s) {
            yr += Hr[s][t] * Zr[s] + Hi[s][t] * Zi[s];
            yi += Hr[s][t] * Zi[s] - Hi[s][t] * Zr[s];
        }
        if (MODE == 0) {
            ((float*)out_raw)[obase + t * SITE] = yr;
        } else {
            ((unsigned int*)out_raw)[obase + t * SITE] =
                (unsigned int)bf16_bits(yr) | ((unsigned int)bf16_bits(yi) << 16);
        }
    }
}

extern "C" void kernel_launch(void* const* d_in, const int* in_sizes, int n_in,
                              void* d_out, int out_size, void* d_ws, size_t ws_size,
                              hipStream_t stream) {
    // Inputs in setup_inputs() dict order (per harness doc):
    //   [0]=x_real, [1]=x_imag, [2]=h_real, [3]=h_imag, [4]=precoding_ind
    const float* xr = (const float*)d_in[0];
    const float* xi = (const float*)d_in[1];
    const float* hr = (const float*)d_in[2];
    const float* hi = (const float*)d_in[3];

    const int grid = (NSITES + 255) / 256;
    if (out_size == NB * NT * SITE) {
        // complex64 ref stored as float32 (imag dropped): write Re(y) only.
        zf_precoder_kernel<0><<<grid, 256, 0, stream>>>(xr, xi, hr, hi, d_out);
    } else {
        // fallback: bf16 interleaved (re,im)
        zf_precoder_kernel<1><<<grid, 256, 0, stream>>>(xr, xi, hr, hi, d_out);
    }
}

// Round 9
// 27.708 us; speedup vs baseline: 1.0298x; 1.0298x over previous
//
#include <hip/hip_runtime.h>
#include <hip/hip_bf16.h>

// Problem constants: B=16, NTX=1, S=4, OFDM=14, FFT=1024, NRX=4, NRXA=1, T=16.
// precoding_ind = arange(4) -> identity selection (folded into indexing).
#define NB    16
#define NS    4
#define NT    16
#define NOFDM 14
#define NFFT  1024
#define SITE  (NOFDM * NFFT)          // 14336 sites per b
#define NSITES (NB * SITE)            // 229376 threads total
#define BLK   64                      // 1 wave per block: perfect CU balance (3584 blocks)

// RNE float -> bf16 bits (fallback path only)
__device__ __forceinline__ unsigned short bf16_bits(float f) {
    unsigned int u = __float_as_uint(f);
    return (unsigned short)((u + 0x7FFFu + ((u >> 16) & 1u)) >> 16);
}

template <int MODE>   // 0: f32 real-part only (out_size=3670016); 1: bf16 interleaved pairs
__global__ __launch_bounds__(BLK, 2)   // min 2 waves/EU -> VGPR cap 256: keep all of H live
void zf_precoder_kernel(
    const float* __restrict__ xr, const float* __restrict__ xi,
    const float* __restrict__ hr, const float* __restrict__ hi,
    void* __restrict__ out_raw)
{
    const int gid = blockIdx.x * BLK + threadIdx.x;   // site id, exact grid
    const int b   = gid / SITE;
    const int rem = gid - b * SITE;                   // ofdm*NFFT + fft

    // ---- load H (4x16 complex) into registers: h (B,4,1,1,16,OFDM,FFT) ----
    // Issue all 128 loads first: 136 independent in-flight loads per wave is the
    // only latency-hiding this kernel gets (3.5 waves/SIMD total).
    float Hr[NS][NT], Hi[NS][NT];
    const int hbase = b * (NS * NT * SITE) + rem;
    #pragma unroll
    for (int s = 0; s < NS; ++s) {
        #pragma unroll
        for (int t = 0; t < NT; ++t) {
            const int idx = hbase + (s * NT + t) * SITE;
            Hr[s][t] = hr[idx];
            Hi[s][t] = hi[idx];
        }
    }

    // ---- load x (4 complex): x (B,1,S,OFDM,FFT) ----
    float Xr[NS], Xi[NS];
    const int xbase = b * (NS * SITE) + rem;
    #pragma unroll
    for (int s = 0; s < NS; ++s) {
        Xr[s] = xr[xbase + s * SITE];
        Xi[s] = xi[xbase + s * SITE];
    }

    // ---- A = H * H^H (lower triangle, Hermitian) ----
    float Ar[NS][NS], Ai[NS][NS];
    #pragma unroll
    for (int i = 0; i < NS; ++i) {
        #pragma unroll
        for (int j = 0; j <= i; ++j) {
            float sr = 0.f, si = 0.f;
            #pragma unroll
            for (int t = 0; t < NT; ++t) {
                sr += Hr[i][t] * Hr[j][t] + Hi[i][t] * Hi[j][t];
                si += Hi[i][t] * Hr[j][t] - Hr[i][t] * Hi[j][t];
            }
            Ar[i][j] = sr;
            Ai[i][j] = si;
        }
    }

    // ---- complex Cholesky A = L L^H (in-place, 1/diag in invd) ----
    float invd[NS];
    #pragma unroll
    for (int j = 0; j < NS; ++j) {
        float s = Ar[j][j];
        #pragma unroll
        for (int k = 0; k < j; ++k)
            s -= Ar[j][k] * Ar[j][k] + Ai[j][k] * Ai[j][k];
        const float inv = 1.0f / sqrtf(fmaxf(s, 1e-20f));
        invd[j] = inv;
        #pragma unroll
        for (int i = j + 1; i < NS; ++i) {
            float sr = Ar[i][j], si = Ai[i][j];
            #pragma unroll
            for (int k = 0; k < j; ++k) {
                sr -= Ar[i][k] * Ar[j][k] + Ai[i][k] * Ai[j][k];
                si -= Ai[i][k] * Ar[j][k] - Ar[i][k] * Ai[j][k];
            }
            Ar[i][j] = sr * inv;
            Ai[i][j] = si * inv;
        }
    }

    // ---- forward solve L w = x ----
    float Wr[NS], Wi[NS];
    #pragma unroll
    for (int i = 0; i < NS; ++i) {
        float sr = Xr[i], si = Xi[i];
        #pragma unroll
        for (int k = 0; k < i; ++k) {
            sr -= Ar[i][k] * Wr[k] - Ai[i][k] * Wi[k];
            si -= Ar[i][k] * Wi[k] + Ai[i][k] * Wr[k];
        }
        Wr[i] = sr * invd[i];
        Wi[i] = si * invd[i];
    }

    // ---- back solve L^H z = w ----
    float Zr[NS], Zi[NS];
    #pragma unroll
    for (int i = NS - 1; i >= 0; --i) {
        float sr = Wr[i], si = Wi[i];
        #pragma unroll
        for (int k = i + 1; k < NS; ++k) {
            sr -= Ar[k][i] * Zr[k] + Ai[k][i] * Zi[k];
            si -= Ar[k][i] * Zi[k] - Ai[k][i] * Zr[k];
        }
        Zr[i] = sr * invd[i];
        Zi[i] = si * invd[i];
    }

    // ---- y[t] = sum_s conj(H[s][t]) * z[s]; H still live in registers ----
    // Output complex array is (B,1,T,OFDM,FFT); site idx = b*(NT*SITE) + t*SITE + rem.
    const int obase = b * (NT * SITE) + rem;
    #pragma unroll
    for (int t = 0; t < NT; ++t) {
        float yr = 0.f, yi = 0.f;
        #pragma unroll
        for (int s = 0; s < NS; ++s) {
            yr += Hr[s][t] * Zr[s] + Hi[s][t] * Zi[s];
            yi += Hr[s][t] * Zi[s] - Hi[s][t] * Zr[s];
        }
        if (MODE == 0) {
            ((float*)out_raw)[obase + t * SITE] = yr;
        } else {
            ((unsigned int*)out_raw)[obase + t * SITE] =
                (unsigned int)bf16_bits(yr) | ((unsigned int)bf16_bits(yi) << 16);
        }
    }
}

extern "C" void kernel_launch(void* const* d_in, const int* in_sizes, int n_in,
                              void* d_out, int out_size, void* d_ws, size_t ws_size,
                              hipStream_t stream) {
    // Inputs in setup_inputs() dict order:
    //   [0]=x_real, [1]=x_imag, [2]=h_real, [3]=h_imag, [4]=precoding_ind
    const float* xr = (const float*)d_in[0];
    const float* xi = (const float*)d_in[1];
    const float* hr = (const float*)d_in[2];
    const float* hi = (const float*)d_in[3];

    const int grid = NSITES / BLK;   // 3584 blocks, exact
    if (out_size == NB * NT * SITE) {
        // complex64 ref stored as float32 (imag dropped): write Re(y) only.
        zf_precoder_kernel<0><<<grid, BLK, 0, stream>>>(xr, xi, hr, hi, d_out);
    } else {
        // fallback: bf16 interleaved (re,im)
        zf_precoder_kernel<1><<<grid, BLK, 0, stream>>>(xr, xi, hr, hi, d_out);
    }
}

// Round 10
// 27.504 us; speedup vs baseline: 1.0374x; 1.0074x over previous
//
#include <hip/hip_runtime.h>
#include <hip/hip_bf16.h>

// Problem constants: B=16, NTX=1, S=4, OFDM=14, FFT=1024, NRX=4, NRXA=1, T=16.
// precoding_ind = arange(4) -> identity selection (folded into indexing).
#define NB    16
#define NS    4
#define NT    16
#define NOFDM 14
#define NFFT  1024
#define SITE  (NOFDM * NFFT)          // 14336 sites per b
#define NSITES (NB * SITE)            // 229376 threads total
#define BLK   64                      // 1 wave per block: perfect CU balance (3584 blocks)

// RNE float -> bf16 bits (fallback path only)
__device__ __forceinline__ unsigned short bf16_bits(float f) {
    unsigned int u = __float_as_uint(f);
    return (unsigned short)((u + 0x7FFFu + ((u >> 16) & 1u)) >> 16);
}

// Pin a value into a VGPR: the empty asm "may modify" v, so the compiler cannot
// rematerialize the defining load at later uses — forces single global read.
__device__ __forceinline__ void pin(float& v) { asm volatile("" : "+v"(v)); }

template <int MODE>   // 0: f32 real-part only (out_size=3670016); 1: bf16 interleaved pairs
__global__ __launch_bounds__(BLK, 2)   // VGPR cap 256: room for all of H live
void zf_precoder_kernel(
    const float* __restrict__ xr, const float* __restrict__ xi,
    const float* __restrict__ hr, const float* __restrict__ hi,
    void* __restrict__ out_raw)
{
    const int gid = blockIdx.x * BLK + threadIdx.x;   // site id, exact grid
    const int b   = gid / SITE;
    const int rem = gid - b * SITE;                   // ofdm*NFFT + fft

    // ---- load H (4x16 complex) into registers: h (B,4,1,1,16,OFDM,FFT) ----
    // All 128 loads issued up front; pin() forces them to stay in VGPRs so the
    // epilogue reuses registers instead of re-reading 117 MB through L2/L3.
    float Hr[NS][NT], Hi[NS][NT];
    const int hbase = b * (NS * NT * SITE) + rem;
    #pragma unroll
    for (int s = 0; s < NS; ++s) {
        #pragma unroll
        for (int t = 0; t < NT; ++t) {
            const int idx = hbase + (s * NT + t) * SITE;
            Hr[s][t] = hr[idx];
            Hi[s][t] = hi[idx];
        }
    }
    // ---- load x (4 complex): x (B,1,S,OFDM,FFT) ----
    float Xr[NS], Xi[NS];
    const int xbase = b * (NS * SITE) + rem;
    #pragma unroll
    for (int s = 0; s < NS; ++s) {
        Xr[s] = xr[xbase + s * SITE];
        Xi[s] = xi[xbase + s * SITE];
    }
    // Pin everything AFTER all loads are issued (keeps 136 loads in flight).
    #pragma unroll
    for (int s = 0; s < NS; ++s) {
        #pragma unroll
        for (int t = 0; t < NT; ++t) { pin(Hr[s][t]); pin(Hi[s][t]); }
    }

    // ---- A = H * H^H (lower triangle, Hermitian) ----
    float Ar[NS][NS], Ai[NS][NS];
    #pragma unroll
    for (int i = 0; i < NS; ++i) {
        #pragma unroll
        for (int j = 0; j <= i; ++j) {
            float sr = 0.f, si = 0.f;
            #pragma unroll
            for (int t = 0; t < NT; ++t) {
                sr += Hr[i][t] * Hr[j][t] + Hi[i][t] * Hi[j][t];
                si += Hi[i][t] * Hr[j][t] - Hr[i][t] * Hi[j][t];
            }
            Ar[i][j] = sr;
            Ai[i][j] = si;
        }
    }

    // ---- complex Cholesky A = L L^H (in-place, 1/diag in invd) ----
    float invd[NS];
    #pragma unroll
    for (int j = 0; j < NS; ++j) {
        float s = Ar[j][j];
        #pragma unroll
        for (int k = 0; k < j; ++k)
            s -= Ar[j][k] * Ar[j][k] + Ai[j][k] * Ai[j][k];
        const float inv = 1.0f / sqrtf(fmaxf(s, 1e-20f));
        invd[j] = inv;
        #pragma unroll
        for (int i = j + 1; i < NS; ++i) {
            float sr = Ar[i][j], si = Ai[i][j];
            #pragma unroll
            for (int k = 0; k < j; ++k) {
                sr -= Ar[i][k] * Ar[j][k] + Ai[i][k] * Ai[j][k];
                si -= Ai[i][k] * Ar[j][k] - Ar[i][k] * Ai[j][k];
            }
            Ar[i][j] = sr * inv;
            Ai[i][j] = si * inv;
        }
    }

    // ---- forward solve L w = x ----
    float Wr[NS], Wi[NS];
    #pragma unroll
    for (int i = 0; i < NS; ++i) {
        float sr = Xr[i], si = Xi[i];
        #pragma unroll
        for (int k = 0; k < i; ++k) {
            sr -= Ar[i][k] * Wr[k] - Ai[i][k] * Wi[k];
            si -= Ar[i][k] * Wi[k] + Ai[i][k] * Wr[k];
        }
        Wr[i] = sr * invd[i];
        Wi[i] = si * invd[i];
    }

    // ---- back solve L^H z = w ----
    float Zr[NS], Zi[NS];
    #pragma unroll
    for (int i = NS - 1; i >= 0; --i) {
        float sr = Wr[i], si = Wi[i];
        #pragma unroll
        for (int k = i + 1; k < NS; ++k) {
            sr -= Ar[k][i] * Zr[k] + Ai[k][i] * Zi[k];
            si -= Ar[k][i] * Zi[k] - Ai[k][i] * Zr[k];
        }
        Zr[i] = sr * invd[i];
        Zi[i] = si * invd[i];
    }

    // ---- y[t] = sum_s conj(H[s][t]) * z[s]; H still live in registers ----
    // Output complex array is (B,1,T,OFDM,FFT); site idx = b*(NT*SITE) + t*SITE + rem.
    const int obase = b * (NT * SITE) + rem;
    #pragma unroll
    for (int t = 0; t < NT; ++t) {
        float yr = 0.f, yi = 0.f;
        #pragma unroll
        for (int s = 0; s < NS; ++s) {
            yr += Hr[s][t] * Zr[s] + Hi[s][t] * Zi[s];
            yi += Hr[s][t] * Zi[s] - Hi[s][t] * Zr[s];
        }
        if (MODE == 0) {
            ((float*)out_raw)[obase + t * SITE] = yr;
        } else {
            ((unsigned int*)out_raw)[obase + t * SITE] =
                (unsigned int)bf16_bits(yr) | ((unsigned int)bf16_bits(yi) << 16);
        }
    }
}

extern "C" void kernel_launch(void* const* d_in, const int* in_sizes, int n_in,
                              void* d_out, int out_size, void* d_ws, size_t ws_size,
                              hipStream_t stream) {
    // Inputs in setup_inputs() dict order:
    //   [0]=x_real, [1]=x_imag, [2]=h_real, [3]=h_imag, [4]=precoding_ind
    const float* xr = (const float*)d_in[0];
    const float* xi = (const float*)d_in[1];
    const float* hr = (const float*)d_in[2];
    const float* hi = (const float*)d_in[3];

    const int grid = NSITES / BLK;   // 3584 blocks, exact
    if (out_size == NB * NT * SITE) {
        // complex64 ref stored as float32 (imag dropped): write Re(y) only.
        zf_precoder_kernel<0><<<grid, BLK, 0, stream>>>(xr, xi, hr, hi, d_out);
    } else {
        // fallback: bf16 interleaved (re,im)
        zf_precoder_kernel<1><<<grid, BLK, 0, stream>>>(xr, xi, hr, hi, d_out);
    }
}